// Round 17
// baseline (321.164 us; speedup 1.0000x reference)
//
#include <hip/hip_runtime.h>
#include <hip/hip_bf16.h>
#include <type_traits>

#define BQ   256
#define NTR  50000
#define DD   3072
#define NSP  50048          // padded N stride (multiple of 64)
#define NBLK 782
#define CAP  4096
#define DELTA 18.0f

typedef __fp16 f16;
typedef __fp16 f16x2 __attribute__((ext_vector_type(2)));
typedef __fp16 f16x4 __attribute__((ext_vector_type(4)));
typedef __fp16 f16x8 __attribute__((ext_vector_type(8)));
typedef float  f32x4 __attribute__((ext_vector_type(4)));

// ---------------- P0: convert x (f32) -> fp16, fragment-major pack ----------------
__global__ __launch_bounds__(256) void kx(const float* __restrict__ x, f16* __restrict__ xp) {
    const int t = blockIdx.x * 256 + threadIdx.x;   // t = g*256 + r, grid = 384*256
    const int g = t >> 8, r = t & 255;
    const f32x4* src = (const f32x4*)(x + (size_t)r * DD + (g << 3));
    f32x4 a = src[0], b = src[1];
    union { f16x2 h2[4]; f16x8 h8; } u;
    u.h2[0] = __builtin_amdgcn_cvt_pkrtz(a[0], a[1]);
    u.h2[1] = __builtin_amdgcn_cvt_pkrtz(a[2], a[3]);
    u.h2[2] = __builtin_amdgcn_cvt_pkrtz(b[0], b[1]);
    u.h2[3] = __builtin_amdgcn_cvt_pkrtz(b[2], b[3]);
    ((f16x8*)xp)[t] = u.h8;
}

// ---------------- P1: S = X*Y^T - 0.5*|y|^2 — producer/consumer wave specialization ----------------
// 12 waves: w=0..7 consumers (MFMA, identical math to r15/r16), w=8..11 producers
// (stream y f32 -> cvt fp16 -> 8-deep LDS ring). Flag protocol (per-slot epochs,
// single-writer volatile LDS): producers never cross a barrier mid-loop, so HBM
// requests stay continuously in flight — removing the sync-coupled stall that
// capped every prior variant at ~3 TB/s.
__global__ __launch_bounds__(768, 3) void kqk(
    const f16* __restrict__ xp, const float* __restrict__ y,
    f16* __restrict__ S, float* __restrict__ pmax) {
    __shared__ __align__(16) char ring[8][8192];   // slot = 64 rows x 128 B fp16, XOR-swizzled
    __shared__ int pflag[8][4];                    // staged epochs per producer wave
    __shared__ int cflag[8][8];                    // consumed epochs per consumer wave
    __shared__ float lysf[64];

    const int tid = threadIdx.x;
    // XCD-chunked bijective swizzle (782 = 6*98 + 2*97)
    const int orig = blockIdx.x;
    const int xcd = orig & 7, cidx = orig >> 3;
    const int blk = (xcd < 6 ? xcd * 98 : 588 + (xcd - 6) * 97) + cidx;
    const int n0  = blk * 64;
    const int w = tid >> 6, l = tid & 63;
    const int l15 = l & 15, lg = l >> 4;

    // flag init
    if (tid < 32) (&pflag[0][0])[tid] = 0;
    else if (tid < 96) (&cflag[0][0])[tid - 32] = 0;
    __syncthreads();

    f32x4 acc[2][4] = {};
    float y2p[4] = {0.f, 0.f, 0.f, 0.f};
    int rowid[4];

    if (w < 8) {
        // ---------------- consumers: MFMA over the ring ----------------
        const f16x8* ap = (const f16x8*)xp;
        const int arow = (w << 5) + l15;    // wave w owns query rows w*32..w*32+31
        for (int ks = 0; ks < 48; ++ks) {
            const int slot = ks & 7, e1 = (ks >> 3) + 1;
            f16x8 af[2][2];
            #pragma unroll
            for (int kk = 0; kk < 2; ++kk)
                #pragma unroll
                for (int fm = 0; fm < 2; ++fm)
                    af[kk][fm] = ap[(size_t)((ks << 3) + (kk << 2) + lg) * 256 + arow + (fm << 4)];
            {   // wait until all 4 producer waves staged this slot's epoch
                volatile int* pf = &pflag[slot][0];
                while (!(pf[0] >= e1 && pf[1] >= e1 && pf[2] >= e1 && pf[3] >= e1))
                    __builtin_amdgcn_s_sleep(2);
            }
            asm volatile("" ::: "memory");
            const char* Bc = ring[slot];
            f16x8 bf[2][4];
            #pragma unroll
            for (int kk = 0; kk < 2; ++kk)
                #pragma unroll
                for (int fn = 0; fn < 4; ++fn) {
                    int r = (fn << 4) + l15;
                    bf[kk][fn] = *(const f16x8*)(&Bc[r * 128 + (((kk << 6) + (lg << 4)) ^ ((r & 7) << 4))]);
                }
            #pragma unroll
            for (int kk = 0; kk < 2; ++kk)
                #pragma unroll
                for (int fm = 0; fm < 2; ++fm)
                    #pragma unroll
                    for (int fn = 0; fn < 4; ++fn)
                        acc[fm][fn] = __builtin_amdgcn_mfma_f32_16x16x32_f16(af[kk][fm], bf[kk][fn], acc[fm][fn], 0, 0, 0);
            asm volatile("s_waitcnt lgkmcnt(0)" ::: "memory");
            if (l == 0) *(volatile int*)&cflag[slot][w] = e1;
        }
    } else {
        // ---------------- producers: stream y, no barriers ----------------
        const int pw = w - 8;               // 0..3: rows pw*16..pw*16+15
        const int r4 = l >> 4;              // 0..3
        const int kc = l & 15;              // 16B f32 chunk within 256B row-step
        const float* yb[4];
        #pragma unroll
        for (int p = 0; p < 4; ++p) {
            int row = (pw << 4) + (p << 2) + r4;
            rowid[p] = row;
            int gr = n0 + row; gr = gr < NTR ? gr : NTR - 1;   // clamp: pads finite, rejected later
            yb[p] = y + (size_t)gr * DD + (kc << 2);
        }
        f32x4 P[4], Q[4];
        auto pload = [&](f32x4 (&D)[4], int ks) {
            #pragma unroll
            for (int p = 0; p < 4; ++p) D[p] = *(const f32x4*)(yb[p] + (ks << 6));
        };
        auto PITER = [&](int ks, f32x4 (&CUR)[4]) {
            const int slot = ks & 7, e = ks >> 3;
            if (e > 0) {    // ring-full gate: all consumers done with this slot's previous epoch
                volatile int* cf = &cflag[slot][0];
                while (!(cf[0] >= e && cf[1] >= e && cf[2] >= e && cf[3] >= e &&
                         cf[4] >= e && cf[5] >= e && cf[6] >= e && cf[7] >= e))
                    __builtin_amdgcn_s_sleep(1);
            }
            asm volatile("" ::: "memory");
            if (ks < 47) asm volatile("s_waitcnt vmcnt(4)" ::: "memory");   // CUR landed, next batch in flight
            else         asm volatile("s_waitcnt vmcnt(0)" ::: "memory");
            #pragma unroll
            for (int p = 0; p < 4; ++p) {
                f32x4 v = CUR[p];
                y2p[p] += v[0]*v[0] + v[1]*v[1] + v[2]*v[2] + v[3]*v[3];
                union { f16x2 h2[2]; f16x4 h4; } u;
                u.h2[0] = __builtin_amdgcn_cvt_pkrtz(v[0], v[1]);
                u.h2[1] = __builtin_amdgcn_cvt_pkrtz(v[2], v[3]);
                int row = rowid[p];
                int bo = row * 128 + ((((kc >> 1) << 4) ^ ((row & 7) << 4)) | ((kc & 1) << 3));
                *(f16x4*)(&ring[slot][bo]) = u.h4;
            }
            asm volatile("s_waitcnt lgkmcnt(0)" ::: "memory");
            if (l == 0) *(volatile int*)&pflag[slot][pw] = e + 1;
            if (ks + 2 < 48) pload(CUR, ks + 2);
        };
        pload(P, 0); pload(Q, 1);
        for (int ks2 = 0; ks2 < 48; ks2 += 2) { PITER(ks2, P); PITER(ks2 + 1, Q); }
        // reduce y2 across the 16 lanes of each row (value valid on all lanes)
        #pragma unroll
        for (int p = 0; p < 4; ++p) {
            float v = y2p[p];
            v += __shfl_xor(v, 1, 64);
            v += __shfl_xor(v, 2, 64);
            v += __shfl_xor(v, 4, 64);
            v += __shfl_xor(v, 8, 64);
            y2p[p] = v;
        }
    }
    __syncthreads();
    if (w >= 8 && (l & 15) == 0) {
        #pragma unroll
        for (int p = 0; p < 4; ++p) lysf[rowid[p]] = y2p[p];
    }
    __syncthreads();

    if (w < 8) {
        // ---------------- consumer epilogue: pmax + fp16 S (r16-identical) ----------------
        float ly2[4];
        #pragma unroll
        for (int fn = 0; fn < 4; ++fn) ly2[fn] = 0.5f * lysf[(fn << 4) + l15];
        #pragma unroll
        for (int fm = 0; fm < 2; ++fm) {
            #pragma unroll
            for (int j = 0; j < 4; ++j) {
                float rm = -3.4e38f;
                #pragma unroll
                for (int fn = 0; fn < 4; ++fn) {
                    int col = n0 + (fn << 4) + l15;
                    float sc = acc[fm][fn][j] - ly2[fn];
                    rm = (col < NTR) ? fmaxf(rm, sc) : rm;
                }
                #pragma unroll
                for (int off = 1; off < 16; off <<= 1) rm = fmaxf(rm, __shfl_xor(rm, off, 64));
                if (l15 == 0)
                    pmax[(size_t)((w << 5) + (fm << 4) + (lg << 2) + j) * NBLK + blk] = rm;
            }
        }
        #pragma unroll
        for (int fm = 0; fm < 2; ++fm) {
            int row0 = (w << 5) + (fm << 4) + (lg << 2);
            #pragma unroll
            for (int fn = 0; fn < 4; ++fn) {
                int col = n0 + (fn << 4) + l15;
                f16* sp = S + (size_t)row0 * NSP + col;
                sp[0]               = (f16)(acc[fm][fn][0] - ly2[fn]);
                sp[NSP]             = (f16)(acc[fm][fn][1] - ly2[fn]);
                sp[2 * (size_t)NSP] = (f16)(acc[fm][fn][2] - ly2[fn]);
                sp[3 * (size_t)NSP] = (f16)(acc[fm][fn][3] - ly2[fn]);
            }
        }
    }
}

// ---------------- P2+P3 fused: max -> scan fp16 S -> exact rescore + online softmax + PV ----------------
__global__ __launch_bounds__(512) void ksp(
    const float* __restrict__ x, const float* __restrict__ y,
    const f16* __restrict__ S, const float* __restrict__ pmax,
    const float* __restrict__ sig, float* __restrict__ out) {
    __shared__ float xs[DD];
    __shared__ unsigned ci[CAP];
    __shared__ unsigned scnt;
    __shared__ float red[8];
    __shared__ float om[8], ol[8];
    __shared__ float sumv[DD];
    const int b = blockIdx.x, tid = threadIdx.x;
    const float s2 = sig[b] * sig[b];
    const float isc = -0.5f / s2;
    const int w = tid >> 6, l = tid & 63;

    if (tid == 0) scnt = 0;
    for (int i = tid; i < DD; i += 512) xs[i] = x[(size_t)b * DD + i];
    const float* pm = pmax + (size_t)b * NBLK;
    float mx = -3.4e38f;
    for (int i = tid; i < NBLK; i += 512) mx = fmaxf(mx, pm[i]);
    #pragma unroll
    for (int o = 1; o < 64; o <<= 1) mx = fmaxf(mx, __shfl_xor(mx, o, 64));
    if (l == 0) red[w] = mx;
    __syncthreads();
    mx = red[0];
    #pragma unroll
    for (int ww = 1; ww < 8; ++ww) mx = fmaxf(mx, red[ww]);
    const float thr = mx - DELTA * s2 - 2.0f;   // fp16-S safety margin

    const f16x8* row = (const f16x8*)(S + (size_t)b * NSP);
    for (int i = tid; i < 6256; i += 512) {      // 6256*8 = 50048
        f16x8 v = row[i];
        #pragma unroll
        for (int j = 0; j < 8; ++j) {
            int idx = (i << 3) + j;
            if ((float)v[j] >= thr && idx < NTR) {
                unsigned p = atomicAdd(&scnt, 1u);
                if (p < CAP) ci[p] = (unsigned)idx;
            }
        }
    }
    __syncthreads();
    const int c = (int)(scnt < (unsigned)CAP ? scnt : (unsigned)CAP);

    const f32x4* xr = (const f32x4*)xs;
    f32x4 o[12] = {};
    float m = -3.4e38f, ll = 0.f;
    f32x4 A[12], Bv[12];

    auto LD = [&](f32x4* dst, int i) {
        const f32x4* yr = (const f32x4*)(y + (size_t)ci[i] * DD);
        #pragma unroll
        for (int j = 0; j < 12; ++j) dst[j] = yr[(j << 6) + l];
    };
    auto PROC = [&](f32x4* src) {
        float d2 = 0.f;
        #pragma unroll
        for (int j = 0; j < 12; ++j) {
            f32x4 xv = xr[(j << 6) + l];
            float a0 = xv[0]-src[j][0], a1 = xv[1]-src[j][1],
                  a2 = xv[2]-src[j][2], a3 = xv[3]-src[j][3];
            d2 += a0*a0 + a1*a1 + a2*a2 + a3*a3;
        }
        #pragma unroll
        for (int off = 1; off < 64; off <<= 1) d2 += __shfl_xor(d2, off, 64);
        float s = d2 * isc;
        float mn = fmaxf(m, s);
        float f = __expf(m - mn);
        float wi = __expf(s - mn);
        #pragma unroll
        for (int j = 0; j < 12; ++j) o[j] = o[j] * f + wi * src[j];
        ll = ll * f + wi;
        m = mn;
    };

    int i = w;
    if (i < c) LD(A, i);
    for (; i < c; i += 16) {
        int i2 = i + 8;
        if (i2 < c) LD(Bv, i2);
        PROC(A);
        if (i2 < c) {
            if (i + 16 < c) LD(A, i + 16);
            PROC(Bv);
        }
    }
    om[w] = m; ol[w] = ll;
    __syncthreads();
    float M = om[0];
    #pragma unroll
    for (int ww = 1; ww < 8; ++ww) M = fmaxf(M, om[ww]);
    float Ls = 0.f;
    #pragma unroll
    for (int ww = 0; ww < 8; ++ww) Ls += ol[ww] * __expf(om[ww] - M);
    const float fw = __expf(m - M);
    f32x4* sv = (f32x4*)sumv;
    if (w == 0) {
        #pragma unroll
        for (int j = 0; j < 12; ++j) sv[(j << 6) + l] = o[j] * fw;
    }
    __syncthreads();
    for (int ww = 1; ww < 8; ++ww) {
        if (w == ww) {
            #pragma unroll
            for (int j = 0; j < 12; ++j) sv[(j << 6) + l] += o[j] * fw;
        }
        __syncthreads();
    }
    const float inv = 1.f / Ls;
    f32x4* od = (f32x4*)(out + (size_t)b * DD);
    for (int t = tid; t < 768; t += 512) od[t] = sv[t] * inv;
}

extern "C" void kernel_launch(void* const* d_in, const int* in_sizes, int n_in,
                              void* d_out, int out_size, void* d_ws, size_t ws_size,
                              hipStream_t stream) {
    const float* x   = (const float*)d_in[0];
    const float* sig = (const float*)d_in[1];
    const float* y   = (const float*)d_in[2];
    float* out = (float*)d_out;
    char* ws = (char*)d_ws;
    f16*   xp   = (f16*)(ws);                   // 1,572,864
    float* pmax = (float*)(ws + 1572864);       // 256*782*4 = 800,768
    f16*   S    = (f16*)(ws + 2373632);         // 256*50048*2 = 25,624,576

    kx  <<<384, 256, 0, stream>>>(x, xp);
    kqk <<<NBLK, 768, 0, stream>>>(xp, y, S, pmax);
    ksp <<<256, 512, 0, stream>>>(x, y, S, pmax, sig, out);
}